// Round 3
// baseline (538.845 us; speedup 1.0000x reference)
//
#include <hip/hip_runtime.h>
#include <stdint.h>
#include <stddef.h>

#define B_ROWS 16384
#define DIN 1024
#define DOUT 1024
#define KDIM 2048   // DIN + DOUT

#define BM 256      // rows per block
#define BNP 256     // packed cols per block = 4 groups x (4 gates x 16 cols)
#define BK 64       // K per tile; 32 K-tiles total

typedef __bf16 bf16x8 __attribute__((ext_vector_type(8)));
typedef float floatx4 __attribute__((ext_vector_type(4)));

__device__ __forceinline__ unsigned short f2bf(float f) {
  unsigned int u = __float_as_uint(f);
  u += 0x7fffu + ((u >> 16) & 1u);   // round-to-nearest-even
  return (unsigned short)(u >> 16);
}

// NOTE: offset arg MUST stay 0 — nonzero builtin offset was the R2 NaN
// suspect. K-offsets are folded into the global pointer instead; the
// compiler re-folds constants into the instruction offset field safely.
__device__ __forceinline__ void async16(const void* g, void* l) {
  __builtin_amdgcn_global_load_lds(
      (__attribute__((address_space(1))) void*)(g),
      (__attribute__((address_space(3))) void*)(l), 16, 0, 0);
}

__device__ __forceinline__ float sigmoid_f(float x) {
  return 1.0f / (1.0f + __expf(-x));
}
__device__ __forceinline__ float tanh_f(float x) {
  return 2.0f / (1.0f + __expf(-2.0f * x)) - 1.0f;
}

// ---------------- prep (single launch): cast X + transpose/pack W ----------
// blocks [0, 32768): cast & concat X = [inputs | hist] -> bf16 16384 x 2048
// blocks [32768, 40960): transpose W into gate-packed n-major layout:
//   packed row np = (n>>4)*64 + g*16 + (n&15), row length KDIM (k-major).
//   One GEMM wave (64 packed rows) = all 4 gates for the same 16 cols.
//   z = 2*g + part; part0 = Wx (k 0..1023), part1 = Wh (k 1024..2047)
__global__ void prep_kernel(
    const float* __restrict__ inp, const float* __restrict__ hist,
    const float* __restrict__ s0, const float* __restrict__ s1,
    const float* __restrict__ s2, const float* __restrict__ s3,
    const float* __restrict__ s4, const float* __restrict__ s5,
    const float* __restrict__ s6, const float* __restrict__ s7,
    unsigned short* __restrict__ xb, unsigned short* __restrict__ wt) {
  __shared__ float tile[32][33];
  const int tid = threadIdx.x;
  if (blockIdx.x < 32768) {
    int idx = blockIdx.x * 256 + tid;           // one float4 per thread
    const int per = B_ROWS * DIN / 4;
    const float* src;
    int colOff;
    int i = idx;
    if (i < per) { src = inp; colOff = 0; }
    else         { src = hist; colOff = DIN; i -= per; }
    int e = i * 4;
    int row = e >> 10;
    int col = e & 1023;
    const float4 v = *(const float4*)(src + (size_t)row * 1024 + col);
    ushort4 o;
    o.x = f2bf(v.x); o.y = f2bf(v.y); o.z = f2bf(v.z); o.w = f2bf(v.w);
    *(ushort4*)(xb + (size_t)row * KDIM + colOff + col) = o;
    return;
  }
  const int bb = blockIdx.x - 32768;            // 0..8191 = 32 x 32 x 8
  const int bx = bb & 31, by = (bb >> 5) & 31, z = bb >> 10;
  const float* src;
  switch (z) {
    case 0: src = s0; break; case 1: src = s1; break;
    case 2: src = s2; break; case 3: src = s3; break;
    case 4: src = s4; break; case 5: src = s5; break;
    case 6: src = s6; break; default: src = s7; break;
  }
  const int g = z >> 1, part = z & 1;
  const int tx = tid & 31, ty = tid >> 5;       // 32 x 8
  const int n0 = bx * 32, k0 = by * 32;
#pragma unroll
  for (int j = 0; j < 32; j += 8)
    tile[ty + j][tx] = src[(size_t)(k0 + ty + j) * DOUT + n0 + tx];
  __syncthreads();
#pragma unroll
  for (int j = 0; j < 32; j += 8) {
    const int n = n0 + ty + j;
    const int np = ((n >> 4) << 6) + g * 16 + (n & 15);
    wt[(size_t)np * KDIM + part * DIN + k0 + tx] = f2bf(tile[tx][ty + j]);
  }
}

// ---------------- fused 4-gate GEMM + LSTM epilogue, super-phase pipeline --
// 256x256(packed) tile, 512 thr / 8 waves (2M x 4N), wave tile 128 x 64.
// LDS regions: As/Bs[buf][khalf][256][32] bf16 (16 KiB each); chunk-XOR
//   swizzle: slot (row,u) holds global chunk u ^ ((row>>1)&3).
// 2 super-phases per K-tile t (buf = t&1):
//   SP(kh): issue bv[0..3] then av[0..7] (12 ds_read_b128, bv FIRST so the
//           mi-outer MFMA order steps lgkmcnt 7->0, one read per 4 MFMAs);
//           STAGE one (tile,kh) unit (4 global_load_lds, ptr + const elems);
//           vmcnt(8); bar; 32 MFMA (setprio); bar.
// Stage ledger (each target freed at the immediately preceding end-bar):
//   SP0(t) stages k1(t+1) -> (buf^1,k1)   [last read SP1(t-1)]
//   SP1(t) stages k0(t+2) -> (buf,  k0)   [last read SP0(t)]
// vmcnt(8): 12 loads in flight, certifies the unit staged 3 SPs ago; the
// certified unit is exactly the one read after the next barrier. In-order
// vmcnt retire => extra interleaved VMEM ops can only strengthen the wait.
#define FENCE() __builtin_amdgcn_sched_barrier(0)
#define BAR() do { FENCE(); __builtin_amdgcn_s_barrier(); FENCE(); } while (0)
#define WAITV(N) asm volatile("s_waitcnt vmcnt(" #N ")" ::: "memory")
#define REGOFF(BUF, KH) (((BUF) * 2 + (KH)) << 13)

// stage one (tile,kh) unit: A rows 0-127/128-255, B same. OFFE is a
// compile-time ELEMENT offset from the advancing per-thread base pointers.
#define STAGE(BUF, KH, OFFE) do {                                           \
    unsigned short* dA_ = As + REGOFF(BUF, KH) + tid * 8;                   \
    unsigned short* dB_ = Bs + REGOFF(BUF, KH) + tid * 8;                   \
    async16(pA0 + (OFFE), dA_);                                             \
    async16(pA1 + (OFFE), dA_ + 4096);                                      \
    async16(pB0 + (OFFE), dB_);                                             \
    async16(pB1 + (OFFE), dB_ + 4096);                                      \
  } while (0)

#define LDB4(BUF, KK) do {                                                  \
    const unsigned short* b_ = Bs + REGOFF(BUF, KK) + boff;                 \
    _Pragma("unroll")                                                       \
    for (int ni = 0; ni < 4; ++ni)                                          \
      bv[ni] = *(const bf16x8*)(b_ + ni * 512);                             \
  } while (0)
#define LDA8(BUF, KK) do {                                                  \
    const unsigned short* a_ = As + REGOFF(BUF, KK) + aoff;                 \
    _Pragma("unroll")                                                       \
    for (int mi = 0; mi < 8; ++mi)                                          \
      av[mi] = *(const bf16x8*)(a_ + mi * 512);                             \
  } while (0)
#define MFMA32() do {                                                       \
    __builtin_amdgcn_s_setprio(1);                                          \
    _Pragma("unroll")                                                       \
    for (int mi = 0; mi < 8; ++mi)                                          \
      _Pragma("unroll")                                                     \
      for (int ni = 0; ni < 4; ++ni)                                        \
        acc[mi][ni] = __builtin_amdgcn_mfma_f32_16x16x32_bf16(              \
            av[mi], bv[ni], acc[mi][ni], 0, 0, 0);                          \
    __builtin_amdgcn_s_setprio(0);                                          \
  } while (0)

__global__ __launch_bounds__(512, 2) void lstm_fused_kernel(
    const unsigned short* __restrict__ Xb,    // 16384 x 2048 bf16
    const unsigned short* __restrict__ Wt2,   // 4096 x 2048 bf16 packed
    const float* __restrict__ b_f, const float* __restrict__ b_i,
    const float* __restrict__ b_o, const float* __restrict__ b_c,
    const int* __restrict__ carousel,
    float* __restrict__ out) {                // h (16384x1024) then c
  __shared__ unsigned short As[4 * 256 * 32];   // [buf][kh][256][32] = 64 KiB
  __shared__ unsigned short Bs[4 * 256 * 32];   // 64 KiB

  const int tid  = threadIdx.x;
  const int lane = tid & 63;
  const int wave = tid >> 6;
  const int wr   = wave >> 2;               // 0..1  (M half)
  const int wc   = wave & 3;                // 0..3  (N group)
  const int m16  = lane & 15;
  const int quad = lane >> 4;
  const int ua   = quad ^ ((m16 >> 1) & 3); // read-side chunk swizzle
  const int bm   = blockIdx.y * BM;
  const int cg   = blockIdx.x;              // 64-orig-col block

  const unsigned short* Wp = Wt2 + (size_t)cg * BNP * KDIM;

  // epilogue scalars loaded BEFORE any staging so they never perturb vmcnt
  const int col = cg * 64 + wc * 16 + m16;
  const float bfv = b_f[col], biv = b_i[col], bov = b_o[col], bcv = b_c[col];
  const float cf  = (float)carousel[0];
  FENCE();

  // staging bases: unit = 256 rows x 32 cols, 4 loads/thread (A hi/lo, B hi/lo)
  const int srow   = tid >> 2;                            // 0..127
  const int schunk = (tid & 3) ^ ((srow >> 1) & 3);       // source chunk
  const unsigned short* pA0 = Xb + (size_t)(bm + srow) * KDIM + schunk * 8;
  const unsigned short* pA1 = pA0 + (size_t)128 * KDIM;
  const unsigned short* pB0 = Wp + (size_t)srow * KDIM + schunk * 8;
  const unsigned short* pB1 = pB0 + (size_t)128 * KDIM;

  const int aoff = (wr * 128 + m16) * 32 + ua * 8;        // ushort offsets
  const int boff = (wc * 64 + m16) * 32 + ua * 8;

  floatx4 acc[8][4];
#pragma unroll
  for (int mi = 0; mi < 8; ++mi)
#pragma unroll
    for (int ni = 0; ni < 4; ++ni)
      acc[mi][ni] = (floatx4){0.f, 0.f, 0.f, 0.f};

  bf16x8 av[8], bv[4];

  // prologue: stage k0(0), k1(0), k0(1); certify k0(0)
  STAGE(0, 0, 0);       // U1 k0(0)
  STAGE(0, 1, 32);      // U2 k1(0)
  STAGE(1, 0, 64);      // U3 k0(1)
  WAITV(8);
  BAR();

#pragma unroll 1
  for (int p = 0; p < 15; ++p) {            // tiles 0..29, pairs (t0=2p)
    // ---- SP0(t0): buf0, k0 ----
    LDB4(0, 0); LDA8(0, 0);
    STAGE(1, 1, 96);                        // k1(t0+1)
    WAITV(8); BAR();
    MFMA32();
    BAR();
    // ---- SP1(t0): buf0, k1 ----
    LDB4(0, 1); LDA8(0, 1);
    STAGE(0, 0, 128);                       // k0(t0+2)
    WAITV(8); BAR();
    MFMA32();
    BAR();
    // ---- SP0(t1): buf1, k0 ----
    LDB4(1, 0); LDA8(1, 0);
    STAGE(0, 1, 160);                       // k1(t0+2)
    WAITV(8); BAR();
    MFMA32();
    BAR();
    // ---- SP1(t1): buf1, k1 ----
    LDB4(1, 1); LDA8(1, 1);
    STAGE(1, 0, 192);                       // k0(t0+3)
    WAITV(8); BAR();
    MFMA32();
    BAR();
    pA0 += 128; pA1 += 128; pB0 += 128; pB1 += 128;   // advance 2 tiles
  }

  // ---- tile 30 (buf0), base pointers at t=30 ----
  LDB4(0, 0); LDA8(0, 0);
  STAGE(1, 1, 96);                          // U64 k1(31) - last unit
  WAITV(8); BAR();
  MFMA32();
  BAR();
  LDB4(0, 1); LDA8(0, 1);
  WAITV(4); BAR();
  MFMA32();
  BAR();
  // ---- tile 31 (buf1): final drain ----
  LDB4(1, 0); LDA8(1, 0);
  WAITV(0); BAR();
  MFMA32();
  BAR();
  LDB4(1, 1); LDA8(1, 1);
  MFMA32();

  // epilogue: n-frag ni == gate (f,i,o,c) for this wave's 16-col group
  const int rbase = bm + wr * 128 + quad * 4;
#pragma unroll
  for (int mi = 0; mi < 8; ++mi) {
#pragma unroll
    for (int r = 0; r < 4; ++r) {
      const int row = rbase + mi * 16 + r;
      const float f = sigmoid_f(acc[mi][0][r] + bfv);
      const float i = sigmoid_f(acc[mi][1][r] + biv);
      const float o = sigmoid_f(acc[mi][2][r] + bov);
      const float g = tanh_f   (acc[mi][3][r] + bcv);
      const float c = f * cf + i * g;
      const float h = o * c;
      out[(size_t)row * DOUT + col] = h;
      out[(size_t)(B_ROWS * DOUT) + (size_t)row * DOUT + col] = c;
    }
  }
}

extern "C" void kernel_launch(void* const* d_in, const int* in_sizes, int n_in,
                              void* d_out, int out_size, void* d_ws, size_t ws_size,
                              hipStream_t stream) {
  const float* inputs = (const float*)d_in[0];
  const float* hist   = (const float*)d_in[1];
  const int* carousel = (const int*)d_in[2];
  const float* Wfx = (const float*)d_in[3];
  const float* Wfh = (const float*)d_in[4];
  const float* bfv = (const float*)d_in[5];
  const float* Wix = (const float*)d_in[6];
  const float* Wih = (const float*)d_in[7];
  const float* biv = (const float*)d_in[8];
  const float* Wox = (const float*)d_in[9];
  const float* Woh = (const float*)d_in[10];
  const float* bov = (const float*)d_in[11];
  const float* Wcx = (const float*)d_in[12];
  const float* Wch = (const float*)d_in[13];
  const float* bcv = (const float*)d_in[14];

  unsigned short* Xb  = (unsigned short*)d_ws;               // 64 MB
  unsigned short* Wt2 = Xb + (size_t)B_ROWS * KDIM;          // 16 MB

  prep_kernel<<<40960, 256, 0, stream>>>(
      inputs, hist, Wfx, Wfh, Wix, Wih, Wox, Woh, Wcx, Wch, Xb, Wt2);

  dim3 grid(16, B_ROWS / BM);                                // 16 x 64 = 1024
  lstm_fused_kernel<<<grid, 512, 0, stream>>>(
      Xb, Wt2, bfv, biv, bov, bcv, carousel, (float*)d_out);
}

// Round 4
// 515.981 us; speedup vs baseline: 1.0443x; 1.0443x over previous
//
#include <hip/hip_runtime.h>
#include <stdint.h>
#include <stddef.h>

#define B_ROWS 16384
#define DIN 1024
#define DOUT 1024
#define KDIM 2048   // DIN + DOUT

#define BM 128
#define BNP 128     // packed N per block = 4 gates x 32 cols
#define BK 64

typedef __bf16 bf16x8 __attribute__((ext_vector_type(8)));
typedef float floatx4 __attribute__((ext_vector_type(4)));

__device__ __forceinline__ unsigned short f2bf(float f) {
  unsigned int u = __float_as_uint(f);
  u += 0x7fffu + ((u >> 16) & 1u);   // round-to-nearest-even
  return (unsigned short)(u >> 16);
}

__device__ __forceinline__ void async16(const void* g, void* l) {
  __builtin_amdgcn_global_load_lds(
      (__attribute__((address_space(1))) void*)(g),
      (__attribute__((address_space(3))) void*)(l), 16, 0, 0);
}

__device__ __forceinline__ float sigmoid_f(float x) {
  return 1.0f / (1.0f + __expf(-x));
}
__device__ __forceinline__ float tanh_f(float x) {
  return 2.0f / (1.0f + __expf(-2.0f * x)) - 1.0f;
}

// ---------------- prep (single launch): cast X + transpose/pack W ----------
// blocks [0, 32768): cast & concat X = [inputs | hist] -> bf16 16384 x 2048
// blocks [32768, 40960): transpose W into gate-packed n-major layout:
//   packed row np = (n>>5)*128 + g*32 + (n&31), row length KDIM (k-major).
//   One GEMM block (128 packed rows) = all 4 gates for the same 32 cols.
//   z = 2*g + part; part0 = Wx (k 0..1023), part1 = Wh (k 1024..2047)
__global__ void prep_kernel(
    const float* __restrict__ inp, const float* __restrict__ hist,
    const float* __restrict__ s0, const float* __restrict__ s1,
    const float* __restrict__ s2, const float* __restrict__ s3,
    const float* __restrict__ s4, const float* __restrict__ s5,
    const float* __restrict__ s6, const float* __restrict__ s7,
    unsigned short* __restrict__ xb, unsigned short* __restrict__ wt) {
  __shared__ float tile[32][33];
  const int tid = threadIdx.x;
  if (blockIdx.x < 32768) {
    int idx = blockIdx.x * 256 + tid;           // one float4 per thread
    const int per = B_ROWS * DIN / 4;
    const float* src;
    int colOff;
    int i = idx;
    if (i < per) { src = inp; colOff = 0; }
    else         { src = hist; colOff = DIN; i -= per; }
    int e = i * 4;
    int row = e >> 10;
    int col = e & 1023;
    const float4 v = *(const float4*)(src + (size_t)row * 1024 + col);
    ushort4 o;
    o.x = f2bf(v.x); o.y = f2bf(v.y); o.z = f2bf(v.z); o.w = f2bf(v.w);
    *(ushort4*)(xb + (size_t)row * KDIM + colOff + col) = o;
    return;
  }
  const int bb = blockIdx.x - 32768;            // 0..8191 = 32 x 32 x 8
  const int bx = bb & 31, by = (bb >> 5) & 31, z = bb >> 10;
  const float* src;
  switch (z) {
    case 0: src = s0; break; case 1: src = s1; break;
    case 2: src = s2; break; case 3: src = s3; break;
    case 4: src = s4; break; case 5: src = s5; break;
    case 6: src = s6; break; default: src = s7; break;
  }
  const int g = z >> 1, part = z & 1;
  const int tx = tid & 31, ty = tid >> 5;       // 32 x 8
  const int n0 = bx * 32, k0 = by * 32;
#pragma unroll
  for (int j = 0; j < 32; j += 8)
    tile[ty + j][tx] = src[(size_t)(k0 + ty + j) * DOUT + n0 + tx];
  __syncthreads();
#pragma unroll
  for (int j = 0; j < 32; j += 8) {
    const int n = n0 + ty + j;
    const int np = ((n >> 5) << 7) + g * 32 + (n & 31);
    wt[(size_t)np * KDIM + part * DIN + k0 + tx] = f2bf(tile[tx][ty + j]);
  }
}

// ---- single-pass 4-gate GEMM + LSTM epilogue ----
// Block: 128 rows x 32 output cols x 4 gates (packed N=128).
// Waves partition M: wave tile 32 x 128 -> 2 m-frags x 8 n-frags,
// ni -> gate = ni>>1, cs = ni&1; every thread holds f,i,o,c for the
// same (row,col) -> direct combine in epilogue, no persistent state.
// LDS XOR-swizzle: slot (row,t) holds global chunk t^(row&7).
// __launch_bounds__(256,4): V+A capped at 128/wave -> 4 blocks/CU
// (R0 was 68 VGPR + 64 AGPR = 132 -> 3 blocks/CU; LDS allows 5).
__global__ __launch_bounds__(256, 4) void lstm_fused_kernel(
    const unsigned short* __restrict__ Xb,    // 16384 x 2048 bf16
    const unsigned short* __restrict__ Wt2,   // 4096 x 2048 bf16 packed
    const float* __restrict__ b_f, const float* __restrict__ b_i,
    const float* __restrict__ b_o, const float* __restrict__ b_c,
    const int* __restrict__ carousel,
    float* __restrict__ out) {                // h (16384x1024) then c
  __shared__ unsigned short As[BM * BK];
  __shared__ unsigned short Bs[BNP * BK];

  const int tid  = threadIdx.x;
  const int lane = tid & 63;
  const int wave = tid >> 6;
  const int wm   = wave * 32;
  const int m16  = lane & 15;
  const int quad = lane >> 4;
  const int r7   = m16 & 7;
  const int bm   = blockIdx.y * BM;
  const int cg   = blockIdx.x;              // 32-col output group

  const unsigned short* Wp = Wt2 + (size_t)cg * BNP * KDIM;

  floatx4 acc[2][8];
#pragma unroll
  for (int mi = 0; mi < 2; ++mi)
#pragma unroll
    for (int ni = 0; ni < 8; ++ni)
      acc[mi][ni] = (floatx4){0.f, 0.f, 0.f, 0.f};

  // staging indices (swizzled global source chunk per LDS slot)
  int srow[4], scol[4];
#pragma unroll
  for (int j = 0; j < 4; ++j) {
    const int c = j * 256 + tid;
    srow[j] = c >> 3;
    scol[j] = (c & 7) ^ (srow[j] & 7);
  }

  for (int kt = 0; kt < KDIM; kt += BK) {
#pragma unroll
    for (int j = 0; j < 4; ++j) {
      const int c = j * 256 + tid;
      async16(Xb + (size_t)(bm + srow[j]) * KDIM + kt + scol[j] * 8, As + c * 8);
    }
#pragma unroll
    for (int j = 0; j < 4; ++j) {
      const int c = j * 256 + tid;
      async16(Wp + (size_t)srow[j] * KDIM + kt + scol[j] * 8, Bs + c * 8);
    }
    __syncthreads();
#pragma unroll
    for (int kk = 0; kk < 2; ++kk) {
      const int t = (kk * 4 + quad) ^ r7;
      bf16x8 av[2], bv[8];
#pragma unroll
      for (int mi = 0; mi < 2; ++mi)
        av[mi] = *(const bf16x8*)(As + (wm + mi * 16 + m16) * BK + t * 8);
#pragma unroll
      for (int ni = 0; ni < 8; ++ni)
        bv[ni] = *(const bf16x8*)(Bs + (ni * 16 + m16) * BK + t * 8);
#pragma unroll
      for (int mi = 0; mi < 2; ++mi)
#pragma unroll
        for (int ni = 0; ni < 8; ++ni)
          acc[mi][ni] = __builtin_amdgcn_mfma_f32_16x16x32_bf16(
              av[mi], bv[ni], acc[mi][ni], 0, 0, 0);
    }
    __syncthreads();
  }

  // epilogue: combine gates, write h and c
  const float cf = (float)carousel[0];
  float bfv[2], biv[2], bov[2], bcv[2];
#pragma unroll
  for (int cs = 0; cs < 2; ++cs) {
    const int col = cg * 32 + cs * 16 + m16;
    bfv[cs] = b_f[col]; biv[cs] = b_i[col];
    bov[cs] = b_o[col]; bcv[cs] = b_c[col];
  }

#pragma unroll
  for (int mi = 0; mi < 2; ++mi) {
#pragma unroll
    for (int cs = 0; cs < 2; ++cs) {
      const int col = cg * 32 + cs * 16 + m16;
#pragma unroll
      for (int r = 0; r < 4; ++r) {
        const int row = bm + wm + mi * 16 + quad * 4 + r;
        const float f = sigmoid_f(acc[mi][0 + cs][r] + bfv[cs]);
        const float i = sigmoid_f(acc[mi][2 + cs][r] + biv[cs]);
        const float o = sigmoid_f(acc[mi][4 + cs][r] + bov[cs]);
        const float g = tanh_f   (acc[mi][6 + cs][r] + bcv[cs]);
        const float c = f * cf + i * g;
        const float h = o * c;
        out[(size_t)row * DOUT + col] = h;
        out[(size_t)(B_ROWS * DOUT) + (size_t)row * DOUT + col] = c;
      }
    }
  }
}

extern "C" void kernel_launch(void* const* d_in, const int* in_sizes, int n_in,
                              void* d_out, int out_size, void* d_ws, size_t ws_size,
                              hipStream_t stream) {
  const float* inputs = (const float*)d_in[0];
  const float* hist   = (const float*)d_in[1];
  const int* carousel = (const int*)d_in[2];
  const float* Wfx = (const float*)d_in[3];
  const float* Wfh = (const float*)d_in[4];
  const float* bfv = (const float*)d_in[5];
  const float* Wix = (const float*)d_in[6];
  const float* Wih = (const float*)d_in[7];
  const float* biv = (const float*)d_in[8];
  const float* Wox = (const float*)d_in[9];
  const float* Woh = (const float*)d_in[10];
  const float* bov = (const float*)d_in[11];
  const float* Wcx = (const float*)d_in[12];
  const float* Wch = (const float*)d_in[13];
  const float* bcv = (const float*)d_in[14];

  unsigned short* Xb  = (unsigned short*)d_ws;               // 64 MB
  unsigned short* Wt2 = Xb + (size_t)B_ROWS * KDIM;          // 16 MB

  prep_kernel<<<40960, 256, 0, stream>>>(
      inputs, hist, Wfx, Wfh, Wix, Wih, Wox, Woh, Wcx, Wch, Xb, Wt2);

  dim3 grid(DOUT / 32, B_ROWS / BM);                         // 32 x 128
  lstm_fused_kernel<<<grid, 256, 0, stream>>>(
      Xb, Wt2, bfv, biv, bov, bcv, carousel, (float*)d_out);
}